// Round 19
// baseline (1512.187 us; speedup 1.0000x reference)
//
#include <hip/hip_runtime.h>
#include <hip/hip_bf16.h>
#include <cstdint>

// Problem constants
constexpr int Bb = 8, Cc = 256, Hh = 64, Ww = 64, Nn = 4096;
constexpr int KD = 128, VD = 256, HP = 66; // HP = padded spatial (64+2)

typedef __attribute__((ext_vector_type(8))) short short8_t;   // 8 bf16 MFMA frag
typedef __attribute__((ext_vector_type(4))) short shortx4;    // 4 bf16 packed store
typedef __attribute__((ext_vector_type(4))) float floatx4;    // 16x16 accumulator
typedef __attribute__((ext_vector_type(16))) float f32x16;    // 32x32 accumulator

// kScale = log2(e)/sqrt(128). Softmax column factor exp2(-kScale*sq_j) cancels
// in normalization -> P' = exp2(2*kScale*dot - kScale*sq_i), out = V P'/colsum.
constexpr float kScale = 0.08838834764831845f * 1.4426950408889634f;
constexpr float kTwoK  = 2.0f * kScale;

static __device__ __forceinline__ ushort f2bf(float f) {
    union { float f; uint32_t u; } v{f};
    uint32_t r = v.u + 0x7FFFu + ((v.u >> 16) & 1u);  // RNE
    return (ushort)(r >> 16);
}
static __device__ __forceinline__ float bf2f(ushort b) {
    union { uint32_t u; float f; } v{(uint32_t)b << 16};
    return v.f;
}
// pack two f32 -> two bf16 in one u32 (RNE), single HW inst
static __device__ __forceinline__ uint32_t pk_bf16(float a, float b) {
    uint32_t r;
    asm("v_cvt_pk_bf16_f32 %0, %1, %2" : "=v"(r) : "v"(a), "v"(b));
    return r;
}
// raw v_exp_f32 (2^x)
static __device__ __forceinline__ float exp2_raw(float x) {
    float r;
    asm("v_exp_f32 %0, %1" : "=v"(r) : "v"(x));
    return r;
}
// v_permlane32_swap_b32: a' = {a.lo, b.lo}, b' = {a.hi, b.hi}
// s_nop guards the VALU-write -> permlane-read hazard
static __device__ __forceinline__ void plane32_swap(uint32_t& a, uint32_t& b) {
    asm volatile("s_nop 1\n\tv_permlane32_swap_b32 %0, %1" : "+v"(a), "+v"(b));
}

// async global->LDS, 16B per lane; lds base must be wave-uniform (HW adds lane*16)
static __device__ __forceinline__ void gload_lds16(const void* g, void* l) {
    __builtin_amdgcn_global_load_lds((const __attribute__((address_space(1))) uint32_t*)g,
                                     (__attribute__((address_space(3))) uint32_t*)l, 16, 0, 0);
}

// ---------------------------------------------------------------------------
// K1: x[b][c][y][x] (f32) -> xpad[b][y+1][x+1][c] (bf16, channel-last).
// Border zeroing folded in (no separate memset launch).
__global__ __launch_bounds__(256) void pad_transpose(const float* __restrict__ x,
                                                     ushort* __restrict__ xpad) {
    int bid = blockIdx.x;
    int b = bid & 7, rest = bid >> 3;
    int y = rest & 63, cg = rest >> 6;   // cg: 64-channel group
    int t = threadIdx.x;
    __shared__ float tile[64][65];
    int xcol = t & 63;
    int crow = t >> 6;  // 0..3
    const float* xb = x + ((size_t)(b * Cc + cg * 64) * Nn) + y * 64;
#pragma unroll
    for (int i = 0; i < 16; i++) {
        int c = crow + i * 4;
        tile[c][xcol] = xb[(size_t)c * Nn + xcol];
    }

    // border zeroing for this (b, cg) slice
    ushort* xbb = xpad + ((size_t)b * HP * HP) * Cc + cg * 64;
    if (y == 0) {
        for (int idx = t; idx < HP * 64; idx += 256) {
            int xx = idx >> 6, c = idx & 63;
            xbb[(size_t)xx * Cc + c] = 0;                         // row 0
        }
    }
    if (y == 63) {
        for (int idx = t; idx < HP * 64; idx += 256) {
            int xx = idx >> 6, c = idx & 63;
            xbb[((size_t)65 * HP + xx) * Cc + c] = 0;             // row 65
        }
    }
    {
        int c = t & 63, which = t >> 6;
        if (which < 2) {
            int xx = which * 65;                                  // cols 0, 65
            xbb[((size_t)(y + 1) * HP + xx) * Cc + c] = 0;
        }
    }

    __syncthreads();
    int c = t & 63;
    int x4 = t >> 6;
    ushort* dst = xpad + (((size_t)(b * HP + (y + 1)) * HP) + 1) * Cc + cg * 64 + c;
#pragma unroll
    for (int i = 0; i < 16; i++) {
        int xx = x4 + i * 4;
        dst[(size_t)xx * Cc] = f2bf(tile[c][xx]);
    }
}

// ---------------------------------------------------------------------------
// K2: repack weights w[oc][c][3][3] (f32) -> wt[r][oc][c] (bf16), r = dy*3+dx
__global__ __launch_bounds__(256) void repack_w(const float* __restrict__ kw,
                                                const float* __restrict__ vw,
                                                ushort* __restrict__ wtk,
                                                ushort* __restrict__ wtv) {
    int idx = blockIdx.x * 256 + threadIdx.x;
    const int nk = KD * Cc;   // 32768
    const int nv = VD * Cc;   // 65536
    if (idx < nk) {
        const float* src = kw + (size_t)idx * 9;
        int oc = idx / Cc, c = idx % Cc;
#pragma unroll
        for (int r = 0; r < 9; r++) wtk[((size_t)r * KD + oc) * Cc + c] = f2bf(src[r]);
    } else if (idx < nk + nv) {
        int j = idx - nk;
        const float* src = vw + (size_t)j * 9;
        int oc = j / Cc, c = j % Cc;
#pragma unroll
        for (int r = 0; r < 9; r++) wtv[((size_t)r * VD + oc) * Cc + c] = f2bf(src[r]);
    }
}

// ---------------------------------------------------------------------------
// K3a: key conv (OC=128), ONE row/block (512 blocks -> 2/CU), weight slab
// LDS-staged. Epilogue fuses sq2 = kScale * sum(bf16(kt)^2).  [r14-proven]
__global__ __launch_bounds__(256) void conv_k(const ushort* __restrict__ xpad,
                                              const ushort* __restrict__ wt,
                                              const float* __restrict__ bias,
                                              ushort* __restrict__ kt_out,
                                              float* __restrict__ sq_out) {
    int bid = blockIdx.x;
    int b = bid & 7, y = bid >> 3;
    int lane = threadIdx.x & 63, wv = threadIdx.x >> 6;
    int l15 = lane & 15, g = lane >> 4;
    const int swzA = l15 & 7;

    __shared__ ushort wslab[2][128 * 128];   // 2 x 32KB weight half-slabs

    size_t wsoff[8];
    int ldsrow[8];
#pragma unroll
    for (int h = 0; h < 8; h++) {
        int row = wv * 32 + h * 4 + (lane >> 4);      // oc row this lane stages
        wsoff[h] = (size_t)row * Cc + (((lane & 15) ^ (row & 7)) * 8);
        ldsrow[h] = (wv * 32 + h * 4) * 128;
    }

    floatx4 acc[8];
#pragma unroll
    for (int m = 0; m < 8; m++) acc[m] = (floatx4){0.f, 0.f, 0.f, 0.f};

    const ushort* xb = xpad + ((size_t)b * HP * HP) * Cc;
    int xcol = wv * 16 + l15;  // output x position (wave's 16 columns)

    auto stage = [&](int hs, int bi) {
        int r = hs >> 1, hc = hs & 1;
        const ushort* wb = wt + ((size_t)r * KD) * Cc + hc * 128;
#pragma unroll
        for (int h = 0; h < 8; h++)
            gload_lds16(wb + wsoff[h], &wslab[bi][ldsrow[h]]);
    };

    stage(0, 0);
    __syncthreads();   // implicit vmcnt(0): slab 0 resident

#pragma unroll 1
    for (int hs = 0; hs < 18; ++hs) {
        int bi = hs & 1;
        if (hs < 17) stage(hs + 1, bi ^ 1);   // prefetch; drained by end barrier

        int r = hs >> 1, hc = hs & 1;
        int dy = r / 3, dx = r % 3;
        const ushort* bsrc = xb + ((size_t)(y + dy) * HP + xcol + dx) * Cc + hc * 128 + g * 8;
#pragma unroll
        for (int cc = 0; cc < 4; cc++) {      // 4 k-steps of 32 channels
            short8_t bfrag = *(const short8_t*)(bsrc + cc * 32);
#pragma unroll
            for (int m = 0; m < 8; m++) {
                short8_t afrag = *(const short8_t*)&wslab[bi][(m * 16 + l15) * 128 + ((cc * 4 + g) ^ swzA) * 8];
                acc[m] = __builtin_amdgcn_mfma_f32_16x16x32_bf16(afrag, bfrag, acc[m], 0, 0, 0);
            }
        }
        __syncthreads();   // reads done + prefetch drained
    }

    int pos = y * 64 + xcol;
    ushort* kt = kt_out + ((size_t)(b * Nn + pos)) * KD;
    float ssum = 0.f;
#pragma unroll
    for (int m = 0; m < 8; m++) {
        floatx4 bv = *(const floatx4*)(bias + m * 16 + g * 4);
        shortx4 pk;
#pragma unroll
        for (int r = 0; r < 4; r++) {
            pk[r] = (short)f2bf(acc[m][r] + bv[r]);
            float q = bf2f((ushort)pk[r]);   // bf16-rounded (diag-exact sq)
            ssum += q * q;
        }
        *(shortx4*)(kt + m * 16 + g * 4) = pk;
    }
    ssum += __shfl_xor(ssum, 16, 64);
    ssum += __shfl_xor(ssum, 32, 64);
    if (g == 0) sq_out[b * Nn + pos] = ssum * kScale;
}

// ---------------------------------------------------------------------------
// K3b: value conv (OC=256), TWO rows/block (512 blocks -> 2/CU).  [r14-proven]
__global__ __launch_bounds__(256) void conv_v(const ushort* __restrict__ xpad,
                                              const ushort* __restrict__ wt,
                                              const float* __restrict__ bias,
                                              float* __restrict__ f32_out,
                                              ushort* __restrict__ vb_out) {
    int bid = blockIdx.x;
    int b = bid & 7;
    int ocg = (bid >> 3) & 1;
    int y0 = (bid >> 4) * 2;
    int lane = threadIdx.x & 63, wv = threadIdx.x >> 6;
    int l15 = lane & 15, g = lane >> 4;
    int oc0 = ocg * 128;
    const int swzA = l15 & 7;

    __shared__ ushort wslab[2][128 * 128];   // 2 x 32KB weight half-slabs

    size_t wsoff[8];
    int ldsrow[8];
#pragma unroll
    for (int h = 0; h < 8; h++) {
        int row = wv * 32 + h * 4 + (lane >> 4);      // oc row this lane stages
        wsoff[h] = (size_t)row * Cc + (((lane & 15) ^ (row & 7)) * 8);
        ldsrow[h] = (wv * 32 + h * 4) * 128;
    }

    floatx4 acc[8][2];
#pragma unroll
    for (int m = 0; m < 8; m++)
#pragma unroll
        for (int rr = 0; rr < 2; rr++) acc[m][rr] = (floatx4){0.f, 0.f, 0.f, 0.f};

    const ushort* xb = xpad + ((size_t)b * HP * HP) * Cc;
    int xcol = wv * 16 + l15;  // output x position (wave's 16 columns)

    auto stage = [&](int hs, int bi) {
        int r = hs >> 1, hc = hs & 1;
        const ushort* wb = wt + ((size_t)r * VD + oc0) * Cc + hc * 128;
#pragma unroll
        for (int h = 0; h < 8; h++)
            gload_lds16(wb + wsoff[h], &wslab[bi][ldsrow[h]]);
    };

    stage(0, 0);
    __syncthreads();   // implicit vmcnt(0): slab 0 resident

#pragma unroll 1
    for (int hs = 0; hs < 18; ++hs) {
        int bi = hs & 1;
        if (hs < 17) stage(hs + 1, bi ^ 1);   // prefetch; drained by end barrier

        int r = hs >> 1, hc = hs & 1;
        int dy = r / 3, dx = r % 3;
        const ushort* bsrc0 = xb + ((size_t)(y0 + dy) * HP + xcol + dx) * Cc + hc * 128 + g * 8;
        const ushort* bsrc1 = bsrc0 + (size_t)HP * Cc;   // row y0+1
#pragma unroll
        for (int cc = 0; cc < 4; cc++) {      // 4 k-steps of 32 channels
            short8_t bfragA = *(const short8_t*)(bsrc0 + cc * 32);
            short8_t bfragB = *(const short8_t*)(bsrc1 + cc * 32);
#pragma unroll
            for (int m = 0; m < 8; m++) {
                short8_t afrag = *(const short8_t*)&wslab[bi][(m * 16 + l15) * 128 + ((cc * 4 + g) ^ swzA) * 8];
                acc[m][0] = __builtin_amdgcn_mfma_f32_16x16x32_bf16(afrag, bfragA, acc[m][0], 0, 0, 0);
                acc[m][1] = __builtin_amdgcn_mfma_f32_16x16x32_bf16(afrag, bfragB, acc[m][1], 0, 0, 0);
            }
        }
        __syncthreads();   // reads done + prefetch drained
    }

#pragma unroll
    for (int rr = 0; rr < 2; rr++) {
        int pos = (y0 + rr) * 64 + xcol;
#pragma unroll
        for (int m = 0; m < 8; m++) {
            floatx4 bv = *(const floatx4*)(bias + oc0 + m * 16 + g * 4);
#pragma unroll
            for (int r = 0; r < 4; r++) {
                int oc = oc0 + m * 16 + g * 4 + r;
                float v = acc[m][rr][r] + bv[r];
                f32_out[((size_t)(b * 512 + oc)) * Nn + pos] = v;       // d_out f32
                vb_out[((size_t)(b * VD + oc)) * Nn + pos] = f2bf(v);   // bf16 for PV
            }
        }
    }
}

// ---------------------------------------------------------------------------
// K5: fused attention with 32x32x16 MFMA. r18 structure with the iw-offset
// BUG FIXED: the PV V-read must select the wave's i-half columns —
// unit = iw*4 + k2*2 + h (r18 dropped iw*4, so iw=1 waves multiplied their
// P (i in [32,64)) against V columns [0,32): absmax 1.96).
__global__ __launch_bounds__(256, 2) void attn_kernel(const ushort* __restrict__ kt,
                                                      const ushort* __restrict__ vb,
                                                      const float* __restrict__ sq2,
                                                      float* __restrict__ out) {
    int bid = blockIdx.x;
    int b = bid & 7, jt = bid >> 3;
    int lane = threadIdx.x & 63, wv = threadIdx.x >> 6;
    int l31 = lane & 31, h = lane >> 5, l15 = lane & 15;

    __shared__ ushort bufK[64 * 128];      // 16KB [row][16 units ^(row&15)]
    __shared__ ushort bufV[256 * 64];      // 32KB [vd][8 units ^(vd&7)]
    __shared__ float dls[2][2][32];        // dsum exchange [iw][jg][j]

    const int iw = wv >> 1, jg = wv & 1;

    const ushort* ktb = kt + ((size_t)b * Nn) * KD;
    const ushort* vbb = vb + ((size_t)b * VD) * Nn;
    const float* sqb = sq2 + b * Nn;

    // K staging: phys row = wv*16 + hh*4 + (lane>>4), source unit = l15^(row&15)
    const ushort* skp[4];
#pragma unroll
    for (int hh = 0; hh < 4; hh++) {
        int row = wv * 16 + hh * 4 + (lane >> 4);
        skp[hh] = ktb + (size_t)row * KD + ((l15 ^ (row & 15)) * 8);
    }
    const ushort* svp[8];
#pragma unroll
    for (int hh = 0; hh < 8; hh++) {
        int vd = wv * 64 + hh * 8 + (lane >> 3);
        svp[hh] = vbb + (size_t)vd * Nn + (((lane & 7) ^ (vd & 7)) * 8);
    }

    // kj B-frags: col j = l31, k = ks*16 + 8h + e
    int j = jt * 64 + jg * 32 + l31;
    short8_t kj[8];
#pragma unroll
    for (int ks = 0; ks < 8; ks++)
        kj[ks] = *(const short8_t*)(ktb + (size_t)j * KD + ks * 16 + h * 8);

    f32x16 acc[8];
#pragma unroll
    for (int m = 0; m < 8; m++) acc[m] = (f32x16)(0.f);
    float dsum = 0.f;
    const int swzK = l31 & 15;   // = (iw*32 + l31) & 15
    const int swzV = l31 & 7;

    // prologue: stage K(0), V(0)
#pragma unroll
    for (int hh = 0; hh < 4; hh++) gload_lds16(skp[hh], &bufK[(wv * 16 + hh * 4) * 128]);
#pragma unroll
    for (int hh = 0; hh < 8; hh++) gload_lds16(svp[hh], &bufV[(wv * 64 + hh * 8) * 64]);
    __syncthreads();   // implicit vmcnt(0): both tiles resident

#pragma unroll 1
    for (int it = 0; it < 64; ++it) {
        int i0 = it * 64;

        // S-phase: 8 A-reads (row iw*32+l31, unit (ks*2+h)^swzK), 8 MFMA
        f32x16 sacc = (f32x16)(0.f);
#pragma unroll
        for (int ks = 0; ks < 8; ks++) {
            short8_t afr = *(const short8_t*)&bufK[(iw * 32 + l31) * 128 + (((ks * 2 + h) ^ swzK) * 8)];
            sacc = __builtin_amdgcn_mfma_f32_32x32x16_bf16(afr, kj[ks], sacc, 0, 0, 0);
        }
        __syncthreads();   // sync1: all waves done reading bufK

        // K(it+1) prefetch (drains at sync2; window = transform + PV)
        if (it < 63) {
#pragma unroll
            for (int hh = 0; hh < 4; hh++)
                gload_lds16(skp[hh] + (size_t)(i0 + 64) * KD, &bufK[(wv * 16 + hh * 4) * 128]);
        }

        // transform: sacc[4q+s] holds i_loc = 8q + 4h + s (within wave's 32)
        uint32_t w[4][2];
#pragma unroll
        for (int q = 0; q < 4; q++) {
            floatx4 sqi = *(const floatx4*)(sqb + i0 + iw * 32 + q * 8 + h * 4);
            float p0 = exp2_raw(sacc[4 * q + 0] * kTwoK - sqi[0]);
            float p1 = exp2_raw(sacc[4 * q + 1] * kTwoK - sqi[1]);
            float p2 = exp2_raw(sacc[4 * q + 2] * kTwoK - sqi[2]);
            float p3 = exp2_raw(sacc[4 * q + 3] * kTwoK - sqi[3]);
            dsum += (p0 + p1) + (p2 + p3);
            w[q][0] = pk_bf16(p0, p1);
            w[q][1] = pk_bf16(p2, p3);
        }
        // build PV B-frags: 2 permlane32_swap per kstep.
        // swap(w[2k2][d], w[2k2+1][d]): result0 = B dword d, result1 = dword 2+d
        short8_t pfr[2];
#pragma unroll
        for (int k2 = 0; k2 < 2; k2++) {
            uint32_t a0 = w[2 * k2][0], b0 = w[2 * k2 + 1][0];
            uint32_t a1 = w[2 * k2][1], b1 = w[2 * k2 + 1][1];
            plane32_swap(a0, b0);
            plane32_swap(a1, b1);
            union { uint32_t u[4]; short8_t s; } pu;
            pu.u[0] = a0; pu.u[1] = a1; pu.u[2] = b0; pu.u[3] = b1;
            pfr[k2] = pu.s;
        }

        // PV: 16 V-reads — unit = iw*4 + k2*2 + h (THE r18 FIX), 16 MFMA
#pragma unroll
        for (int k2 = 0; k2 < 2; k2++) {
#pragma unroll
            for (int m = 0; m < 8; m++) {
                int row = m * 32 + l31;
                short8_t vfr = *(const short8_t*)&bufV[row * 64 + (((iw * 4 + k2 * 2 + h) ^ swzV) * 8)];
                acc[m] = __builtin_amdgcn_mfma_f32_32x32x16_bf16(vfr, pfr[k2], acc[m], 0, 0, 0);
            }
        }
        __syncthreads();   // sync2: bufV reads done; K prefetch drained

        // V(it+1) prefetch (drains at next iter's sync1)
        if (it < 63) {
#pragma unroll
            for (int hh = 0; hh < 8; hh++)
                gload_lds16(svp[hh] + (i0 + 64), &bufV[(wv * 64 + hh * 8) * 64]);
        }
    }

    // denominator: combine h halves, then iw halves via dls
    dsum += __shfl_xor(dsum, 32, 64);
    if (lane < 32) dls[iw][jg][l31] = dsum;
    __syncthreads();
    float rden = 1.f / (dls[0][jg][l31] + dls[1][jg][l31]);

    // combine iw partial accumulators through bufV-as-scratch (2 phases)
    float* scratch = (float*)bufV;
#pragma unroll 1
    for (int ph = 0; ph < 2; ph++) {
        if (iw == 1) {
#pragma unroll
            for (int mm = 0; mm < 4; mm++)
#pragma unroll
                for (int r = 0; r < 16; r++)
                    scratch[((jg * 4 + mm) * 16 + r) * 64 + lane] = acc[ph * 4 + mm][r];
        }
        __syncthreads();
        if (iw == 0) {
#pragma unroll
            for (int mm = 0; mm < 4; mm++)
#pragma unroll
                for (int r = 0; r < 16; r++)
                    acc[ph * 4 + mm][r] += scratch[((jg * 4 + mm) * 16 + r) * 64 + lane];
        }
        __syncthreads();
    }

    // output (iw==0 waves): vd = m*32 + (r&3) + 8*(r>>2) + 4h, col j
    if (iw == 0) {
        float* ob = out + ((size_t)(b * 512 + 256)) * Nn + j;
#pragma unroll
        for (int m = 0; m < 8; m++) {
#pragma unroll
            for (int r = 0; r < 16; r++) {
                int vd = m * 32 + (r & 3) + 8 * (r >> 2) + 4 * h;
                ob[(size_t)vd * Nn] = acc[m][r] * rden;
            }
        }
    }
}

// ---------------------------------------------------------------------------
extern "C" void kernel_launch(void* const* d_in, const int* in_sizes, int n_in,
                              void* d_out, int out_size, void* d_ws, size_t ws_size,
                              hipStream_t stream) {
    const float* x     = (const float*)d_in[0];
    const float* kw    = (const float*)d_in[1];
    const float* kbias = (const float*)d_in[2];
    const float* vw    = (const float*)d_in[3];
    const float* vbias = (const float*)d_in[4];
    float* out = (float*)d_out;  // reference output dtype is FLOAT32
    char* ws = (char*)d_ws;

    // workspace layout (bytes) — total 44,908,544
    constexpr size_t XPAD = 0;                         // 8*66*66*256*2 = 17,842,176
    constexpr size_t WTK  = 17842176;                  // 9*128*256*2   =    589,824
    constexpr size_t WTV  = 18432000;                  // 9*256*256*2   =  1,179,648
    constexpr size_t KT   = 19611648;                  // 8*4096*128*2  =  8,388,608
    constexpr size_t VB   = 28000256;                  // 8*256*4096*2  = 16,777,216
    constexpr size_t SQ   = 44777472;                  // 8*4096*4      =    131,072

    ushort* xpad = (ushort*)(ws + XPAD);
    ushort* wtk  = (ushort*)(ws + WTK);
    ushort* wtv  = (ushort*)(ws + WTV);
    ushort* ktw  = (ushort*)(ws + KT);
    ushort* vbw  = (ushort*)(ws + VB);
    float*  sqw  = (float*)(ws + SQ);

    pad_transpose<<<dim3(2048), 256, 0, stream>>>(x, xpad);
    repack_w<<<dim3(384), 256, 0, stream>>>(kw, vw, wtk, wtv);
    conv_k<<<dim3(512), 256, 0, stream>>>(xpad, wtk, kbias, ktw, sqw);
    conv_v<<<dim3(512), 256, 0, stream>>>(xpad, wtv, vbias, out, vbw);
    attn_kernel<<<dim3(512), 256, 0, stream>>>(ktw, vbw, sqw, out);
}

// Round 20
// 1162.764 us; speedup vs baseline: 1.3005x; 1.3005x over previous
//
#include <hip/hip_runtime.h>
#include <hip/hip_bf16.h>
#include <cstdint>

// Problem constants
constexpr int Bb = 8, Cc = 256, Hh = 64, Ww = 64, Nn = 4096;
constexpr int KD = 128, VD = 256, HP = 66; // HP = padded spatial (64+2)

typedef __attribute__((ext_vector_type(8))) short short8_t;   // 8 bf16 MFMA frag
typedef __attribute__((ext_vector_type(4))) short shortx4;    // 4 bf16 packed store
typedef __attribute__((ext_vector_type(4))) float floatx4;    // 16x16 accumulator
typedef __attribute__((ext_vector_type(16))) float f32x16;    // 32x32 accumulator

// kScale = log2(e)/sqrt(128). Softmax column factor exp2(-kScale*sq_j) cancels
// in normalization -> P' = exp2(2*kScale*dot - kScale*sq_i), out = V P'/colsum.
constexpr float kScale = 0.08838834764831845f * 1.4426950408889634f;
constexpr float kTwoK  = 2.0f * kScale;

static __device__ __forceinline__ ushort f2bf(float f) {
    union { float f; uint32_t u; } v{f};
    uint32_t r = v.u + 0x7FFFu + ((v.u >> 16) & 1u);  // RNE
    return (ushort)(r >> 16);
}
static __device__ __forceinline__ float bf2f(ushort b) {
    union { uint32_t u; float f; } v{(uint32_t)b << 16};
    return v.f;
}
// pack two f32 -> two bf16 in one u32 (RNE), single HW inst
static __device__ __forceinline__ uint32_t pk_bf16(float a, float b) {
    uint32_t r;
    asm("v_cvt_pk_bf16_f32 %0, %1, %2" : "=v"(r) : "v"(a), "v"(b));
    return r;
}
// raw v_exp_f32 (2^x)
static __device__ __forceinline__ float exp2_raw(float x) {
    float r;
    asm("v_exp_f32 %0, %1" : "=v"(r) : "v"(x));
    return r;
}
// v_permlane32_swap_b32: a' = {a.lo, b.lo}, b' = {a.hi, b.hi}
// s_nop guards the VALU-write -> permlane-read hazard
static __device__ __forceinline__ void plane32_swap(uint32_t& a, uint32_t& b) {
    asm volatile("s_nop 1\n\tv_permlane32_swap_b32 %0, %1" : "+v"(a), "+v"(b));
}

// async global->LDS, 16B per lane; lds base must be wave-uniform (HW adds lane*16)
static __device__ __forceinline__ void gload_lds16(const void* g, void* l) {
    __builtin_amdgcn_global_load_lds((const __attribute__((address_space(1))) uint32_t*)g,
                                     (__attribute__((address_space(3))) uint32_t*)l, 16, 0, 0);
}

// ---------------------------------------------------------------------------
// K1: x[b][c][y][x] (f32) -> xpad[b][y+1][x+1][c] (bf16, channel-last).
// Border zeroing folded in (no separate memset launch).
__global__ __launch_bounds__(256) void pad_transpose(const float* __restrict__ x,
                                                     ushort* __restrict__ xpad) {
    int bid = blockIdx.x;
    int b = bid & 7, rest = bid >> 3;
    int y = rest & 63, cg = rest >> 6;   // cg: 64-channel group
    int t = threadIdx.x;
    __shared__ float tile[64][65];
    int xcol = t & 63;
    int crow = t >> 6;  // 0..3
    const float* xb = x + ((size_t)(b * Cc + cg * 64) * Nn) + y * 64;
#pragma unroll
    for (int i = 0; i < 16; i++) {
        int c = crow + i * 4;
        tile[c][xcol] = xb[(size_t)c * Nn + xcol];
    }

    // border zeroing for this (b, cg) slice
    ushort* xbb = xpad + ((size_t)b * HP * HP) * Cc + cg * 64;
    if (y == 0) {
        for (int idx = t; idx < HP * 64; idx += 256) {
            int xx = idx >> 6, c = idx & 63;
            xbb[(size_t)xx * Cc + c] = 0;                         // row 0
        }
    }
    if (y == 63) {
        for (int idx = t; idx < HP * 64; idx += 256) {
            int xx = idx >> 6, c = idx & 63;
            xbb[((size_t)65 * HP + xx) * Cc + c] = 0;             // row 65
        }
    }
    {
        int c = t & 63, which = t >> 6;
        if (which < 2) {
            int xx = which * 65;                                  // cols 0, 65
            xbb[((size_t)(y + 1) * HP + xx) * Cc + c] = 0;
        }
    }

    __syncthreads();
    int c = t & 63;
    int x4 = t >> 6;
    ushort* dst = xpad + (((size_t)(b * HP + (y + 1)) * HP) + 1) * Cc + cg * 64 + c;
#pragma unroll
    for (int i = 0; i < 16; i++) {
        int xx = x4 + i * 4;
        dst[(size_t)xx * Cc] = f2bf(tile[c][xx]);
    }
}

// ---------------------------------------------------------------------------
// K2: repack weights w[oc][c][3][3] (f32) -> wt[r][oc][c] (bf16), r = dy*3+dx
__global__ __launch_bounds__(256) void repack_w(const float* __restrict__ kw,
                                                const float* __restrict__ vw,
                                                ushort* __restrict__ wtk,
                                                ushort* __restrict__ wtv) {
    int idx = blockIdx.x * 256 + threadIdx.x;
    const int nk = KD * Cc;   // 32768
    const int nv = VD * Cc;   // 65536
    if (idx < nk) {
        const float* src = kw + (size_t)idx * 9;
        int oc = idx / Cc, c = idx % Cc;
#pragma unroll
        for (int r = 0; r < 9; r++) wtk[((size_t)r * KD + oc) * Cc + c] = f2bf(src[r]);
    } else if (idx < nk + nv) {
        int j = idx - nk;
        const float* src = vw + (size_t)j * 9;
        int oc = j / Cc, c = j % Cc;
#pragma unroll
        for (int r = 0; r < 9; r++) wtv[((size_t)r * VD + oc) * Cc + c] = f2bf(src[r]);
    }
}

// ---------------------------------------------------------------------------
// K3a: key conv (OC=128), ONE row/block (512 blocks -> 2/CU), weight slab
// LDS-staged. Epilogue fuses sq2 = kScale * sum(bf16(kt)^2).  [r14-proven]
__global__ __launch_bounds__(256) void conv_k(const ushort* __restrict__ xpad,
                                              const ushort* __restrict__ wt,
                                              const float* __restrict__ bias,
                                              ushort* __restrict__ kt_out,
                                              float* __restrict__ sq_out) {
    int bid = blockIdx.x;
    int b = bid & 7, y = bid >> 3;
    int lane = threadIdx.x & 63, wv = threadIdx.x >> 6;
    int l15 = lane & 15, g = lane >> 4;
    const int swzA = l15 & 7;

    __shared__ ushort wslab[2][128 * 128];   // 2 x 32KB weight half-slabs

    size_t wsoff[8];
    int ldsrow[8];
#pragma unroll
    for (int h = 0; h < 8; h++) {
        int row = wv * 32 + h * 4 + (lane >> 4);      // oc row this lane stages
        wsoff[h] = (size_t)row * Cc + (((lane & 15) ^ (row & 7)) * 8);
        ldsrow[h] = (wv * 32 + h * 4) * 128;
    }

    floatx4 acc[8];
#pragma unroll
    for (int m = 0; m < 8; m++) acc[m] = (floatx4){0.f, 0.f, 0.f, 0.f};

    const ushort* xb = xpad + ((size_t)b * HP * HP) * Cc;
    int xcol = wv * 16 + l15;  // output x position (wave's 16 columns)

    auto stage = [&](int hs, int bi) {
        int r = hs >> 1, hc = hs & 1;
        const ushort* wb = wt + ((size_t)r * KD) * Cc + hc * 128;
#pragma unroll
        for (int h = 0; h < 8; h++)
            gload_lds16(wb + wsoff[h], &wslab[bi][ldsrow[h]]);
    };

    stage(0, 0);
    __syncthreads();   // implicit vmcnt(0): slab 0 resident

#pragma unroll 1
    for (int hs = 0; hs < 18; ++hs) {
        int bi = hs & 1;
        if (hs < 17) stage(hs + 1, bi ^ 1);   // prefetch; drained by end barrier

        int r = hs >> 1, hc = hs & 1;
        int dy = r / 3, dx = r % 3;
        const ushort* bsrc = xb + ((size_t)(y + dy) * HP + xcol + dx) * Cc + hc * 128 + g * 8;
#pragma unroll
        for (int cc = 0; cc < 4; cc++) {      // 4 k-steps of 32 channels
            short8_t bfrag = *(const short8_t*)(bsrc + cc * 32);
#pragma unroll
            for (int m = 0; m < 8; m++) {
                short8_t afrag = *(const short8_t*)&wslab[bi][(m * 16 + l15) * 128 + ((cc * 4 + g) ^ swzA) * 8];
                acc[m] = __builtin_amdgcn_mfma_f32_16x16x32_bf16(afrag, bfrag, acc[m], 0, 0, 0);
            }
        }
        __syncthreads();   // reads done + prefetch drained
    }

    int pos = y * 64 + xcol;
    ushort* kt = kt_out + ((size_t)(b * Nn + pos)) * KD;
    float ssum = 0.f;
#pragma unroll
    for (int m = 0; m < 8; m++) {
        floatx4 bv = *(const floatx4*)(bias + m * 16 + g * 4);
        shortx4 pk;
#pragma unroll
        for (int r = 0; r < 4; r++) {
            pk[r] = (short)f2bf(acc[m][r] + bv[r]);
            float q = bf2f((ushort)pk[r]);   // bf16-rounded (diag-exact sq)
            ssum += q * q;
        }
        *(shortx4*)(kt + m * 16 + g * 4) = pk;
    }
    ssum += __shfl_xor(ssum, 16, 64);
    ssum += __shfl_xor(ssum, 32, 64);
    if (g == 0) sq_out[b * Nn + pos] = ssum * kScale;
}

// ---------------------------------------------------------------------------
// K3b: value conv (OC=256), TWO rows/block (512 blocks -> 2/CU).  [r14-proven]
__global__ __launch_bounds__(256) void conv_v(const ushort* __restrict__ xpad,
                                              const ushort* __restrict__ wt,
                                              const float* __restrict__ bias,
                                              float* __restrict__ f32_out,
                                              ushort* __restrict__ vb_out) {
    int bid = blockIdx.x;
    int b = bid & 7;
    int ocg = (bid >> 3) & 1;
    int y0 = (bid >> 4) * 2;
    int lane = threadIdx.x & 63, wv = threadIdx.x >> 6;
    int l15 = lane & 15, g = lane >> 4;
    int oc0 = ocg * 128;
    const int swzA = l15 & 7;

    __shared__ ushort wslab[2][128 * 128];   // 2 x 32KB weight half-slabs

    size_t wsoff[8];
    int ldsrow[8];
#pragma unroll
    for (int h = 0; h < 8; h++) {
        int row = wv * 32 + h * 4 + (lane >> 4);      // oc row this lane stages
        wsoff[h] = (size_t)row * Cc + (((lane & 15) ^ (row & 7)) * 8);
        ldsrow[h] = (wv * 32 + h * 4) * 128;
    }

    floatx4 acc[8][2];
#pragma unroll
    for (int m = 0; m < 8; m++)
#pragma unroll
        for (int rr = 0; rr < 2; rr++) acc[m][rr] = (floatx4){0.f, 0.f, 0.f, 0.f};

    const ushort* xb = xpad + ((size_t)b * HP * HP) * Cc;
    int xcol = wv * 16 + l15;  // output x position (wave's 16 columns)

    auto stage = [&](int hs, int bi) {
        int r = hs >> 1, hc = hs & 1;
        const ushort* wb = wt + ((size_t)r * VD + oc0) * Cc + hc * 128;
#pragma unroll
        for (int h = 0; h < 8; h++)
            gload_lds16(wb + wsoff[h], &wslab[bi][ldsrow[h]]);
    };

    stage(0, 0);
    __syncthreads();   // implicit vmcnt(0): slab 0 resident

#pragma unroll 1
    for (int hs = 0; hs < 18; ++hs) {
        int bi = hs & 1;
        if (hs < 17) stage(hs + 1, bi ^ 1);   // prefetch; drained by end barrier

        int r = hs >> 1, hc = hs & 1;
        int dy = r / 3, dx = r % 3;
        const ushort* bsrc0 = xb + ((size_t)(y0 + dy) * HP + xcol + dx) * Cc + hc * 128 + g * 8;
        const ushort* bsrc1 = bsrc0 + (size_t)HP * Cc;   // row y0+1
#pragma unroll
        for (int cc = 0; cc < 4; cc++) {      // 4 k-steps of 32 channels
            short8_t bfragA = *(const short8_t*)(bsrc0 + cc * 32);
            short8_t bfragB = *(const short8_t*)(bsrc1 + cc * 32);
#pragma unroll
            for (int m = 0; m < 8; m++) {
                short8_t afrag = *(const short8_t*)&wslab[bi][(m * 16 + l15) * 128 + ((cc * 4 + g) ^ swzA) * 8];
                acc[m][0] = __builtin_amdgcn_mfma_f32_16x16x32_bf16(afrag, bfragA, acc[m][0], 0, 0, 0);
                acc[m][1] = __builtin_amdgcn_mfma_f32_16x16x32_bf16(afrag, bfragB, acc[m][1], 0, 0, 0);
            }
        }
        __syncthreads();   // reads done + prefetch drained
    }

#pragma unroll
    for (int rr = 0; rr < 2; rr++) {
        int pos = (y0 + rr) * 64 + xcol;
#pragma unroll
        for (int m = 0; m < 8; m++) {
            floatx4 bv = *(const floatx4*)(bias + oc0 + m * 16 + g * 4);
#pragma unroll
            for (int r = 0; r < 4; r++) {
                int oc = oc0 + m * 16 + g * 4 + r;
                float v = acc[m][rr][r] + bv[r];
                f32_out[((size_t)(b * 512 + oc)) * Nn + pos] = v;       // d_out f32
                vb_out[((size_t)(b * VD + oc)) * Nn + pos] = f2bf(v);   // bf16 for PV
            }
        }
    }
}

// ---------------------------------------------------------------------------
// K5: fused attention, 32x32x16 MFMA (layout VERIFIED in r19), with vd split
// across BLOCKS to kill the r19 register spill: grid 1024 = (b, jt, vh);
// block owns vd in [vh*128, vh*128+128) -> acc[4] f32x16 = 64 VGPR (r19's
// acc[8]=128 spilled: 1.8GB scratch FETCH/dispatch). bufV halves to 16KB ->
// LDS 32.5KB -> 3-4 blocks/CU. Waves: iw = i-half, jg = j-group of 32.
// Per wave-iter: 8 K-reads + 8 MFMA (S), 8 V-reads + 8 MFMA (PV).
// P in registers via cvt_pk + 2 permlane32_swap per kstep (r19-verified).
__global__ __launch_bounds__(256, 2) void attn_kernel(const ushort* __restrict__ kt,
                                                      const ushort* __restrict__ vb,
                                                      const float* __restrict__ sq2,
                                                      float* __restrict__ out) {
    int bid = blockIdx.x;
    int b = bid & 7, rest = bid >> 3;
    int jt = rest & 63, vh = rest >> 6;    // vh: vd-half of this block
    int lane = threadIdx.x & 63, wv = threadIdx.x >> 6;
    int l31 = lane & 31, h = lane >> 5, l15 = lane & 15;

    __shared__ ushort bufK[64 * 128];      // 16KB [row][16 units ^(row&15)]
    __shared__ ushort bufV[128 * 64];      // 16KB [vd-local][8 units ^(vd&7)]
    __shared__ float dls[2][2][32];        // dsum exchange [iw][jg][j]

    const int iw = wv >> 1, jg = wv & 1;

    const ushort* ktb = kt + ((size_t)b * Nn) * KD;
    const ushort* vbb = vb + ((size_t)(b * VD + vh * 128)) * Nn;
    const float* sqb = sq2 + b * Nn;

    // K staging: phys row = wv*16 + hh*4 + (lane>>4), source unit = l15^(row&15)
    const ushort* skp[4];
#pragma unroll
    for (int hh = 0; hh < 4; hh++) {
        int row = wv * 16 + hh * 4 + (lane >> 4);
        skp[hh] = ktb + (size_t)row * KD + ((l15 ^ (row & 15)) * 8);
    }
    // V staging: vd-local rows, 4 chunks/wave (16 rows each... 8 rows/chunk)
    const ushort* svp[4];
#pragma unroll
    for (int hh = 0; hh < 4; hh++) {
        int vdl = wv * 32 + hh * 8 + (lane >> 3);
        svp[hh] = vbb + (size_t)vdl * Nn + (((lane & 7) ^ (vdl & 7)) * 8);
    }

    // kj B-frags: col j = l31, k = ks*16 + 8h + e
    int j = jt * 64 + jg * 32 + l31;
    short8_t kj[8];
#pragma unroll
    for (int ks = 0; ks < 8; ks++)
        kj[ks] = *(const short8_t*)(ktb + (size_t)j * KD + ks * 16 + h * 8);

    f32x16 acc[4];
#pragma unroll
    for (int m = 0; m < 4; m++) acc[m] = (f32x16)(0.f);
    float dsum = 0.f;
    const int swzK = l31 & 15;   // = (iw*32 + l31) & 15
    const int swzV = l31 & 7;

    // prologue: stage K(0), V(0)
#pragma unroll
    for (int hh = 0; hh < 4; hh++) gload_lds16(skp[hh], &bufK[(wv * 16 + hh * 4) * 128]);
#pragma unroll
    for (int hh = 0; hh < 4; hh++) gload_lds16(svp[hh], &bufV[(wv * 32 + hh * 8) * 64]);
    __syncthreads();   // implicit vmcnt(0): both tiles resident

#pragma unroll 1
    for (int it = 0; it < 64; ++it) {
        int i0 = it * 64;

        // S-phase: 8 A-reads (row iw*32+l31, unit (ks*2+h)^swzK), 8 MFMA
        f32x16 sacc = (f32x16)(0.f);
#pragma unroll
        for (int ks = 0; ks < 8; ks++) {
            short8_t afr = *(const short8_t*)&bufK[(iw * 32 + l31) * 128 + (((ks * 2 + h) ^ swzK) * 8)];
            sacc = __builtin_amdgcn_mfma_f32_32x32x16_bf16(afr, kj[ks], sacc, 0, 0, 0);
        }
        __syncthreads();   // sync1: all waves done reading bufK

        // K(it+1) prefetch (drains at sync2; window = transform + PV)
        if (it < 63) {
#pragma unroll
            for (int hh = 0; hh < 4; hh++)
                gload_lds16(skp[hh] + (size_t)(i0 + 64) * KD, &bufK[(wv * 16 + hh * 4) * 128]);
        }

        // transform: sacc[4q+s] holds i_loc = 8q + 4h + s (within wave's 32)
        uint32_t w[4][2];
#pragma unroll
        for (int q = 0; q < 4; q++) {
            floatx4 sqi = *(const floatx4*)(sqb + i0 + iw * 32 + q * 8 + h * 4);
            float p0 = exp2_raw(sacc[4 * q + 0] * kTwoK - sqi[0]);
            float p1 = exp2_raw(sacc[4 * q + 1] * kTwoK - sqi[1]);
            float p2 = exp2_raw(sacc[4 * q + 2] * kTwoK - sqi[2]);
            float p3 = exp2_raw(sacc[4 * q + 3] * kTwoK - sqi[3]);
            dsum += (p0 + p1) + (p2 + p3);
            w[q][0] = pk_bf16(p0, p1);
            w[q][1] = pk_bf16(p2, p3);
        }
        // build PV B-frags: 2 permlane32_swap per kstep (r19-verified)
        short8_t pfr[2];
#pragma unroll
        for (int k2 = 0; k2 < 2; k2++) {
            uint32_t a0 = w[2 * k2][0], b0 = w[2 * k2 + 1][0];
            uint32_t a1 = w[2 * k2][1], b1 = w[2 * k2 + 1][1];
            plane32_swap(a0, b0);
            plane32_swap(a1, b1);
            union { uint32_t u[4]; short8_t s; } pu;
            pu.u[0] = a0; pu.u[1] = a1; pu.u[2] = b0; pu.u[3] = b1;
            pfr[k2] = pu.s;
        }

        // PV: 8 V-reads (vd-local row m*32+l31, unit iw*4+k2*2+h), 8 MFMA
#pragma unroll
        for (int k2 = 0; k2 < 2; k2++) {
#pragma unroll
            for (int m = 0; m < 4; m++) {
                int row = m * 32 + l31;
                short8_t vfr = *(const short8_t*)&bufV[row * 64 + (((iw * 4 + k2 * 2 + h) ^ swzV) * 8)];
                acc[m] = __builtin_amdgcn_mfma_f32_32x32x16_bf16(vfr, pfr[k2], acc[m], 0, 0, 0);
            }
        }
        __syncthreads();   // sync2: bufV reads done; K prefetch drained

        // V(it+1) prefetch (drains at next iter's sync1)
        if (it < 63) {
#pragma unroll
            for (int hh = 0; hh < 4; hh++)
                gload_lds16(svp[hh] + (i0 + 64), &bufV[(wv * 32 + hh * 8) * 64]);
        }
    }

    // denominator: combine h halves, then iw halves via dls
    dsum += __shfl_xor(dsum, 32, 64);
    if (lane < 32) dls[iw][jg][l31] = dsum;
    __syncthreads();
    float rden = 1.f / (dls[0][jg][l31] + dls[1][jg][l31]);

    // combine iw partial accumulators through bufV-as-scratch (2 phases of 2 m)
    float* scratch = (float*)bufV;   // 16KB = 2jg x 2m x 16r x 64 lanes x 4B
#pragma unroll 1
    for (int ph = 0; ph < 2; ph++) {
        if (iw == 1) {
#pragma unroll
            for (int mm = 0; mm < 2; mm++)
#pragma unroll
                for (int r = 0; r < 16; r++)
                    scratch[((jg * 2 + mm) * 16 + r) * 64 + lane] = acc[ph * 2 + mm][r];
        }
        __syncthreads();
        if (iw == 0) {
#pragma unroll
            for (int mm = 0; mm < 2; mm++)
#pragma unroll
                for (int r = 0; r < 16; r++)
                    acc[ph * 2 + mm][r] += scratch[((jg * 2 + mm) * 16 + r) * 64 + lane];
        }
        __syncthreads();
    }

    // output (iw==0 waves): vd = vh*128 + m*32 + (r&3) + 8*(r>>2) + 4h, col j
    if (iw == 0) {
        float* ob = out + ((size_t)(b * 512 + 256 + vh * 128)) * Nn + j;
#pragma unroll
        for (int m = 0; m < 4; m++) {
#pragma unroll
            for (int r = 0; r < 16; r++) {
                int vd = m * 32 + (r & 3) + 8 * (r >> 2) + 4 * h;
                ob[(size_t)vd * Nn] = acc[m][r] * rden;
            }
        }
    }
}

// ---------------------------------------------------------------------------
extern "C" void kernel_launch(void* const* d_in, const int* in_sizes, int n_in,
                              void* d_out, int out_size, void* d_ws, size_t ws_size,
                              hipStream_t stream) {
    const float* x     = (const float*)d_in[0];
    const float* kw    = (const float*)d_in[1];
    const float* kbias = (const float*)d_in[2];
    const float* vw    = (const float*)d_in[3];
    const float* vbias = (const float*)d_in[4];
    float* out = (float*)d_out;  // reference output dtype is FLOAT32
    char* ws = (char*)d_ws;

    // workspace layout (bytes) — total 44,908,544
    constexpr size_t XPAD = 0;                         // 8*66*66*256*2 = 17,842,176
    constexpr size_t WTK  = 17842176;                  // 9*128*256*2   =    589,824
    constexpr size_t WTV  = 18432000;                  // 9*256*256*2   =  1,179,648
    constexpr size_t KT   = 19611648;                  // 8*4096*128*2  =  8,388,608
    constexpr size_t VB   = 28000256;                  // 8*256*4096*2  = 16,777,216
    constexpr size_t SQ   = 44777472;                  // 8*4096*4      =    131,072

    ushort* xpad = (ushort*)(ws + XPAD);
    ushort* wtk  = (ushort*)(ws + WTK);
    ushort* wtv  = (ushort*)(ws + WTV);
    ushort* ktw  = (ushort*)(ws + KT);
    ushort* vbw  = (ushort*)(ws + VB);
    float*  sqw  = (float*)(ws + SQ);

    pad_transpose<<<dim3(2048), 256, 0, stream>>>(x, xpad);
    repack_w<<<dim3(384), 256, 0, stream>>>(kw, vw, wtk, wtv);
    conv_k<<<dim3(512), 256, 0, stream>>>(xpad, wtk, kbias, ktw, sqw);
    conv_v<<<dim3(512), 256, 0, stream>>>(xpad, wtv, vbias, out, vbw);
    attn_kernel<<<dim3(1024), 256, 0, stream>>>(ktw, vbw, sqw, out);
}

// Round 21
// 300.936 us; speedup vs baseline: 5.0249x; 3.8638x over previous
//
#include <hip/hip_runtime.h>
#include <hip/hip_bf16.h>
#include <cstdint>

// Problem constants
constexpr int Bb = 8, Cc = 256, Hh = 64, Ww = 64, Nn = 4096;
constexpr int KD = 128, VD = 256, HP = 66; // HP = padded spatial (64+2)

typedef __attribute__((ext_vector_type(8))) short short8_t;   // 8 bf16 MFMA frag
typedef __attribute__((ext_vector_type(4))) short shortx4;    // 4 bf16 packed store
typedef __attribute__((ext_vector_type(4))) float floatx4;    // 16x16 accumulator
typedef __attribute__((ext_vector_type(16))) float f32x16;    // 32x32 accumulator

// kScale = log2(e)/sqrt(128). Softmax column factor exp2(-kScale*sq_j) cancels
// in normalization -> P' = exp2(2*kScale*dot - kScale*sq_i), out = V P'/colsum.
constexpr float kScale = 0.08838834764831845f * 1.4426950408889634f;
constexpr float kTwoK  = 2.0f * kScale;

static __device__ __forceinline__ ushort f2bf(float f) {
    union { float f; uint32_t u; } v{f};
    uint32_t r = v.u + 0x7FFFu + ((v.u >> 16) & 1u);  // RNE
    return (ushort)(r >> 16);
}
static __device__ __forceinline__ float bf2f(ushort b) {
    union { uint32_t u; float f; } v{(uint32_t)b << 16};
    return v.f;
}
// pack two f32 -> two bf16 in one u32 (RNE), single HW inst
static __device__ __forceinline__ uint32_t pk_bf16(float a, float b) {
    uint32_t r;
    asm("v_cvt_pk_bf16_f32 %0, %1, %2" : "=v"(r) : "v"(a), "v"(b));
    return r;
}
// raw v_exp_f32 (2^x)
static __device__ __forceinline__ float exp2_raw(float x) {
    float r;
    asm("v_exp_f32 %0, %1" : "=v"(r) : "v"(x));
    return r;
}
// v_permlane32_swap_b32: a' = {a.lo, b.lo}, b' = {a.hi, b.hi}
// s_nop guards the VALU-write -> permlane-read hazard
static __device__ __forceinline__ void plane32_swap(uint32_t& a, uint32_t& b) {
    asm volatile("s_nop 1\n\tv_permlane32_swap_b32 %0, %1" : "+v"(a), "+v"(b));
}

// async global->LDS, 16B per lane; lds base must be wave-uniform (HW adds lane*16)
static __device__ __forceinline__ void gload_lds16(const void* g, void* l) {
    __builtin_amdgcn_global_load_lds((const __attribute__((address_space(1))) uint32_t*)g,
                                     (__attribute__((address_space(3))) uint32_t*)l, 16, 0, 0);
}

// ---------------------------------------------------------------------------
// K1: x[b][c][y][x] (f32) -> xpad[b][y+1][x+1][c] (bf16, channel-last).
// Border zeroing folded in (no separate memset launch).
__global__ __launch_bounds__(256) void pad_transpose(const float* __restrict__ x,
                                                     ushort* __restrict__ xpad) {
    int bid = blockIdx.x;
    int b = bid & 7, rest = bid >> 3;
    int y = rest & 63, cg = rest >> 6;   // cg: 64-channel group
    int t = threadIdx.x;
    __shared__ float tile[64][65];
    int xcol = t & 63;
    int crow = t >> 6;  // 0..3
    const float* xb = x + ((size_t)(b * Cc + cg * 64) * Nn) + y * 64;
#pragma unroll
    for (int i = 0; i < 16; i++) {
        int c = crow + i * 4;
        tile[c][xcol] = xb[(size_t)c * Nn + xcol];
    }

    // border zeroing for this (b, cg) slice
    ushort* xbb = xpad + ((size_t)b * HP * HP) * Cc + cg * 64;
    if (y == 0) {
        for (int idx = t; idx < HP * 64; idx += 256) {
            int xx = idx >> 6, c = idx & 63;
            xbb[(size_t)xx * Cc + c] = 0;                         // row 0
        }
    }
    if (y == 63) {
        for (int idx = t; idx < HP * 64; idx += 256) {
            int xx = idx >> 6, c = idx & 63;
            xbb[((size_t)65 * HP + xx) * Cc + c] = 0;             // row 65
        }
    }
    {
        int c = t & 63, which = t >> 6;
        if (which < 2) {
            int xx = which * 65;                                  // cols 0, 65
            xbb[((size_t)(y + 1) * HP + xx) * Cc + c] = 0;
        }
    }

    __syncthreads();
    int c = t & 63;
    int x4 = t >> 6;
    ushort* dst = xpad + (((size_t)(b * HP + (y + 1)) * HP) + 1) * Cc + cg * 64 + c;
#pragma unroll
    for (int i = 0; i < 16; i++) {
        int xx = x4 + i * 4;
        dst[(size_t)xx * Cc] = f2bf(tile[c][xx]);
    }
}

// ---------------------------------------------------------------------------
// K2: repack weights w[oc][c][3][3] (f32) -> wt[r][oc][c] (bf16), r = dy*3+dx
__global__ __launch_bounds__(256) void repack_w(const float* __restrict__ kw,
                                                const float* __restrict__ vw,
                                                ushort* __restrict__ wtk,
                                                ushort* __restrict__ wtv) {
    int idx = blockIdx.x * 256 + threadIdx.x;
    const int nk = KD * Cc;   // 32768
    const int nv = VD * Cc;   // 65536
    if (idx < nk) {
        const float* src = kw + (size_t)idx * 9;
        int oc = idx / Cc, c = idx % Cc;
#pragma unroll
        for (int r = 0; r < 9; r++) wtk[((size_t)r * KD + oc) * Cc + c] = f2bf(src[r]);
    } else if (idx < nk + nv) {
        int j = idx - nk;
        const float* src = vw + (size_t)j * 9;
        int oc = j / Cc, c = j % Cc;
#pragma unroll
        for (int r = 0; r < 9; r++) wtv[((size_t)r * VD + oc) * Cc + c] = f2bf(src[r]);
    }
}

// ---------------------------------------------------------------------------
// K3a: key conv (OC=128), ONE row/block (512 blocks -> 2/CU), weight slab
// LDS-staged. Epilogue fuses sq2 = kScale * sum(bf16(kt)^2).  [r14-proven]
__global__ __launch_bounds__(256) void conv_k(const ushort* __restrict__ xpad,
                                              const ushort* __restrict__ wt,
                                              const float* __restrict__ bias,
                                              ushort* __restrict__ kt_out,
                                              float* __restrict__ sq_out) {
    int bid = blockIdx.x;
    int b = bid & 7, y = bid >> 3;
    int lane = threadIdx.x & 63, wv = threadIdx.x >> 6;
    int l15 = lane & 15, g = lane >> 4;
    const int swzA = l15 & 7;

    __shared__ ushort wslab[2][128 * 128];   // 2 x 32KB weight half-slabs

    size_t wsoff[8];
    int ldsrow[8];
#pragma unroll
    for (int h = 0; h < 8; h++) {
        int row = wv * 32 + h * 4 + (lane >> 4);      // oc row this lane stages
        wsoff[h] = (size_t)row * Cc + (((lane & 15) ^ (row & 7)) * 8);
        ldsrow[h] = (wv * 32 + h * 4) * 128;
    }

    floatx4 acc[8];
#pragma unroll
    for (int m = 0; m < 8; m++) acc[m] = (floatx4){0.f, 0.f, 0.f, 0.f};

    const ushort* xb = xpad + ((size_t)b * HP * HP) * Cc;
    int xcol = wv * 16 + l15;  // output x position (wave's 16 columns)

    auto stage = [&](int hs, int bi) {
        int r = hs >> 1, hc = hs & 1;
        const ushort* wb = wt + ((size_t)r * KD) * Cc + hc * 128;
#pragma unroll
        for (int h = 0; h < 8; h++)
            gload_lds16(wb + wsoff[h], &wslab[bi][ldsrow[h]]);
    };

    stage(0, 0);
    __syncthreads();   // implicit vmcnt(0): slab 0 resident

#pragma unroll 1
    for (int hs = 0; hs < 18; ++hs) {
        int bi = hs & 1;
        if (hs < 17) stage(hs + 1, bi ^ 1);   // prefetch; drained by end barrier

        int r = hs >> 1, hc = hs & 1;
        int dy = r / 3, dx = r % 3;
        const ushort* bsrc = xb + ((size_t)(y + dy) * HP + xcol + dx) * Cc + hc * 128 + g * 8;
#pragma unroll
        for (int cc = 0; cc < 4; cc++) {      // 4 k-steps of 32 channels
            short8_t bfrag = *(const short8_t*)(bsrc + cc * 32);
#pragma unroll
            for (int m = 0; m < 8; m++) {
                short8_t afrag = *(const short8_t*)&wslab[bi][(m * 16 + l15) * 128 + ((cc * 4 + g) ^ swzA) * 8];
                acc[m] = __builtin_amdgcn_mfma_f32_16x16x32_bf16(afrag, bfrag, acc[m], 0, 0, 0);
            }
        }
        __syncthreads();   // reads done + prefetch drained
    }

    int pos = y * 64 + xcol;
    ushort* kt = kt_out + ((size_t)(b * Nn + pos)) * KD;
    float ssum = 0.f;
#pragma unroll
    for (int m = 0; m < 8; m++) {
        floatx4 bv = *(const floatx4*)(bias + m * 16 + g * 4);
        shortx4 pk;
#pragma unroll
        for (int r = 0; r < 4; r++) {
            pk[r] = (short)f2bf(acc[m][r] + bv[r]);
            float q = bf2f((ushort)pk[r]);   // bf16-rounded (diag-exact sq)
            ssum += q * q;
        }
        *(shortx4*)(kt + m * 16 + g * 4) = pk;
    }
    ssum += __shfl_xor(ssum, 16, 64);
    ssum += __shfl_xor(ssum, 32, 64);
    if (g == 0) sq_out[b * Nn + pos] = ssum * kScale;
}

// ---------------------------------------------------------------------------
// K3b: value conv (OC=256), TWO rows/block (512 blocks -> 2/CU).  [r14-proven]
__global__ __launch_bounds__(256) void conv_v(const ushort* __restrict__ xpad,
                                              const ushort* __restrict__ wt,
                                              const float* __restrict__ bias,
                                              float* __restrict__ f32_out,
                                              ushort* __restrict__ vb_out) {
    int bid = blockIdx.x;
    int b = bid & 7;
    int ocg = (bid >> 3) & 1;
    int y0 = (bid >> 4) * 2;
    int lane = threadIdx.x & 63, wv = threadIdx.x >> 6;
    int l15 = lane & 15, g = lane >> 4;
    int oc0 = ocg * 128;
    const int swzA = l15 & 7;

    __shared__ ushort wslab[2][128 * 128];   // 2 x 32KB weight half-slabs

    size_t wsoff[8];
    int ldsrow[8];
#pragma unroll
    for (int h = 0; h < 8; h++) {
        int row = wv * 32 + h * 4 + (lane >> 4);      // oc row this lane stages
        wsoff[h] = (size_t)row * Cc + (((lane & 15) ^ (row & 7)) * 8);
        ldsrow[h] = (wv * 32 + h * 4) * 128;
    }

    floatx4 acc[8][2];
#pragma unroll
    for (int m = 0; m < 8; m++)
#pragma unroll
        for (int rr = 0; rr < 2; rr++) acc[m][rr] = (floatx4){0.f, 0.f, 0.f, 0.f};

    const ushort* xb = xpad + ((size_t)b * HP * HP) * Cc;
    int xcol = wv * 16 + l15;  // output x position (wave's 16 columns)

    auto stage = [&](int hs, int bi) {
        int r = hs >> 1, hc = hs & 1;
        const ushort* wb = wt + ((size_t)r * VD + oc0) * Cc + hc * 128;
#pragma unroll
        for (int h = 0; h < 8; h++)
            gload_lds16(wb + wsoff[h], &wslab[bi][ldsrow[h]]);
    };

    stage(0, 0);
    __syncthreads();   // implicit vmcnt(0): slab 0 resident

#pragma unroll 1
    for (int hs = 0; hs < 18; ++hs) {
        int bi = hs & 1;
        if (hs < 17) stage(hs + 1, bi ^ 1);   // prefetch; drained by end barrier

        int r = hs >> 1, hc = hs & 1;
        int dy = r / 3, dx = r % 3;
        const ushort* bsrc0 = xb + ((size_t)(y0 + dy) * HP + xcol + dx) * Cc + hc * 128 + g * 8;
        const ushort* bsrc1 = bsrc0 + (size_t)HP * Cc;   // row y0+1
#pragma unroll
        for (int cc = 0; cc < 4; cc++) {      // 4 k-steps of 32 channels
            short8_t bfragA = *(const short8_t*)(bsrc0 + cc * 32);
            short8_t bfragB = *(const short8_t*)(bsrc1 + cc * 32);
#pragma unroll
            for (int m = 0; m < 8; m++) {
                short8_t afrag = *(const short8_t*)&wslab[bi][(m * 16 + l15) * 128 + ((cc * 4 + g) ^ swzA) * 8];
                acc[m][0] = __builtin_amdgcn_mfma_f32_16x16x32_bf16(afrag, bfragA, acc[m][0], 0, 0, 0);
                acc[m][1] = __builtin_amdgcn_mfma_f32_16x16x32_bf16(afrag, bfragB, acc[m][1], 0, 0, 0);
            }
        }
        __syncthreads();   // reads done + prefetch drained
    }

#pragma unroll
    for (int rr = 0; rr < 2; rr++) {
        int pos = (y0 + rr) * 64 + xcol;
#pragma unroll
        for (int m = 0; m < 8; m++) {
            floatx4 bv = *(const floatx4*)(bias + oc0 + m * 16 + g * 4);
#pragma unroll
            for (int r = 0; r < 4; r++) {
                int oc = oc0 + m * 16 + g * 4 + r;
                float v = acc[m][rr][r] + bv[r];
                f32_out[((size_t)(b * 512 + oc)) * Nn + pos] = v;       // d_out f32
                vb_out[((size_t)(b * VD + oc)) * Nn + pos] = f2bf(v);   // bf16 for PV
            }
        }
    }
}

// ---------------------------------------------------------------------------
// K5: fused attention, 32x32x16 MFMA, vd split across blocks (r20 geometry).
// THE r20 FIX: epilogue phase loop is FULLY UNROLLED — r20's
// "#pragma unroll 1" made `acc[ph*2+mm]` runtime-indexed, which forces the
// whole f32x16 acc array into scratch for the kernel's lifetime (rule #20);
// every main-loop MFMA then round-tripped acc through HBM (3.9GB writes,
// VGPR_Count 80). All acc indices are now compile-time.
__global__ __launch_bounds__(256, 2) void attn_kernel(const ushort* __restrict__ kt,
                                                      const ushort* __restrict__ vb,
                                                      const float* __restrict__ sq2,
                                                      float* __restrict__ out) {
    int bid = blockIdx.x;
    int b = bid & 7, rest = bid >> 3;
    int jt = rest & 63, vh = rest >> 6;    // vh: vd-half of this block
    int lane = threadIdx.x & 63, wv = threadIdx.x >> 6;
    int l31 = lane & 31, h = lane >> 5, l15 = lane & 15;

    __shared__ ushort bufK[64 * 128];      // 16KB [row][16 units ^(row&15)]
    __shared__ ushort bufV[128 * 64];      // 16KB [vd-local][8 units ^(vd&7)]
    __shared__ float dls[2][2][32];        // dsum exchange [iw][jg][j]

    const int iw = wv >> 1, jg = wv & 1;

    const ushort* ktb = kt + ((size_t)b * Nn) * KD;
    const ushort* vbb = vb + ((size_t)(b * VD + vh * 128)) * Nn;
    const float* sqb = sq2 + b * Nn;

    // K staging: phys row = wv*16 + hh*4 + (lane>>4), source unit = l15^(row&15)
    const ushort* skp[4];
#pragma unroll
    for (int hh = 0; hh < 4; hh++) {
        int row = wv * 16 + hh * 4 + (lane >> 4);
        skp[hh] = ktb + (size_t)row * KD + ((l15 ^ (row & 15)) * 8);
    }
    // V staging: vd-local rows, 4 chunks/wave (8 rows/chunk)
    const ushort* svp[4];
#pragma unroll
    for (int hh = 0; hh < 4; hh++) {
        int vdl = wv * 32 + hh * 8 + (lane >> 3);
        svp[hh] = vbb + (size_t)vdl * Nn + (((lane & 7) ^ (vdl & 7)) * 8);
    }

    // kj B-frags: col j = l31, k = ks*16 + 8h + e
    int j = jt * 64 + jg * 32 + l31;
    short8_t kj[8];
#pragma unroll
    for (int ks = 0; ks < 8; ks++)
        kj[ks] = *(const short8_t*)(ktb + (size_t)j * KD + ks * 16 + h * 8);

    f32x16 acc[4];
#pragma unroll
    for (int m = 0; m < 4; m++) acc[m] = (f32x16)(0.f);
    float dsum = 0.f;
    const int swzK = l31 & 15;   // = (iw*32 + l31) & 15
    const int swzV = l31 & 7;

    // prologue: stage K(0), V(0)
#pragma unroll
    for (int hh = 0; hh < 4; hh++) gload_lds16(skp[hh], &bufK[(wv * 16 + hh * 4) * 128]);
#pragma unroll
    for (int hh = 0; hh < 4; hh++) gload_lds16(svp[hh], &bufV[(wv * 32 + hh * 8) * 64]);
    __syncthreads();   // implicit vmcnt(0): both tiles resident

#pragma unroll 1
    for (int it = 0; it < 64; ++it) {
        int i0 = it * 64;

        // S-phase: 8 A-reads (row iw*32+l31, unit (ks*2+h)^swzK), 8 MFMA
        f32x16 sacc = (f32x16)(0.f);
#pragma unroll
        for (int ks = 0; ks < 8; ks++) {
            short8_t afr = *(const short8_t*)&bufK[(iw * 32 + l31) * 128 + (((ks * 2 + h) ^ swzK) * 8)];
            sacc = __builtin_amdgcn_mfma_f32_32x32x16_bf16(afr, kj[ks], sacc, 0, 0, 0);
        }
        __syncthreads();   // sync1: all waves done reading bufK

        // K(it+1) prefetch (drains at sync2; window = transform + PV)
        if (it < 63) {
#pragma unroll
            for (int hh = 0; hh < 4; hh++)
                gload_lds16(skp[hh] + (size_t)(i0 + 64) * KD, &bufK[(wv * 16 + hh * 4) * 128]);
        }

        // transform: sacc[4q+s] holds i_loc = 8q + 4h + s (within wave's 32)
        uint32_t w[4][2];
#pragma unroll
        for (int q = 0; q < 4; q++) {
            floatx4 sqi = *(const floatx4*)(sqb + i0 + iw * 32 + q * 8 + h * 4);
            float p0 = exp2_raw(sacc[4 * q + 0] * kTwoK - sqi[0]);
            float p1 = exp2_raw(sacc[4 * q + 1] * kTwoK - sqi[1]);
            float p2 = exp2_raw(sacc[4 * q + 2] * kTwoK - sqi[2]);
            float p3 = exp2_raw(sacc[4 * q + 3] * kTwoK - sqi[3]);
            dsum += (p0 + p1) + (p2 + p3);
            w[q][0] = pk_bf16(p0, p1);
            w[q][1] = pk_bf16(p2, p3);
        }
        // build PV B-frags: 2 permlane32_swap per kstep (r19-verified)
        short8_t pfr[2];
#pragma unroll
        for (int k2 = 0; k2 < 2; k2++) {
            uint32_t a0 = w[2 * k2][0], b0 = w[2 * k2 + 1][0];
            uint32_t a1 = w[2 * k2][1], b1 = w[2 * k2 + 1][1];
            plane32_swap(a0, b0);
            plane32_swap(a1, b1);
            union { uint32_t u[4]; short8_t s; } pu;
            pu.u[0] = a0; pu.u[1] = a1; pu.u[2] = b0; pu.u[3] = b1;
            pfr[k2] = pu.s;
        }

        // PV: 8 V-reads (vd-local row m*32+l31, unit iw*4+k2*2+h), 8 MFMA
#pragma unroll
        for (int k2 = 0; k2 < 2; k2++) {
#pragma unroll
            for (int m = 0; m < 4; m++) {
                int row = m * 32 + l31;
                short8_t vfr = *(const short8_t*)&bufV[row * 64 + (((iw * 4 + k2 * 2 + h) ^ swzV) * 8)];
                acc[m] = __builtin_amdgcn_mfma_f32_32x32x16_bf16(vfr, pfr[k2], acc[m], 0, 0, 0);
            }
        }
        __syncthreads();   // sync2: bufV reads done; K prefetch drained

        // V(it+1) prefetch (drains at next iter's sync1)
        if (it < 63) {
#pragma unroll
            for (int hh = 0; hh < 4; hh++)
                gload_lds16(svp[hh] + (i0 + 64), &bufV[(wv * 32 + hh * 8) * 64]);
        }
    }

    // denominator: combine h halves, then iw halves via dls
    dsum += __shfl_xor(dsum, 32, 64);
    if (lane < 32) dls[iw][jg][l31] = dsum;
    __syncthreads();
    float rden = 1.f / (dls[0][jg][l31] + dls[1][jg][l31]);

    // combine iw partial accumulators through bufV-as-scratch.
    // FULLY UNROLLED (compile-time acc indices) — see kernel comment.
    float* scratch = (float*)bufV;   // 16KB = 2jg x 2m x 16r x 64 lanes x 4B
#pragma unroll
    for (int ph = 0; ph < 2; ph++) {
        if (iw == 1) {
#pragma unroll
            for (int mm = 0; mm < 2; mm++)
#pragma unroll
                for (int r = 0; r < 16; r++)
                    scratch[((jg * 2 + mm) * 16 + r) * 64 + lane] = acc[ph * 2 + mm][r];
        }
        __syncthreads();
        if (iw == 0) {
#pragma unroll
            for (int mm = 0; mm < 2; mm++)
#pragma unroll
                for (int r = 0; r < 16; r++)
                    acc[ph * 2 + mm][r] += scratch[((jg * 2 + mm) * 16 + r) * 64 + lane];
        }
        __syncthreads();
    }

    // output (iw==0 waves): vd = vh*128 + m*32 + (r&3) + 8*(r>>2) + 4h, col j
    if (iw == 0) {
        float* ob = out + ((size_t)(b * 512 + 256 + vh * 128)) * Nn + j;
#pragma unroll
        for (int m = 0; m < 4; m++) {
#pragma unroll
            for (int r = 0; r < 16; r++) {
                int vd = m * 32 + (r & 3) + 8 * (r >> 2) + 4 * h;
                ob[(size_t)vd * Nn] = acc[m][r] * rden;
            }
        }
    }
}

// ---------------------------------------------------------------------------
extern "C" void kernel_launch(void* const* d_in, const int* in_sizes, int n_in,
                              void* d_out, int out_size, void* d_ws, size_t ws_size,
                              hipStream_t stream) {
    const float* x     = (const float*)d_in[0];
    const float* kw    = (const float*)d_in[1];
    const float* kbias = (const float*)d_in[2];
    const float* vw    = (const float*)d_in[3];
    const float* vbias = (const float*)d_in[4];
    float* out = (float*)d_out;  // reference output dtype is FLOAT32
    char* ws = (char*)d_ws;

    // workspace layout (bytes) — total 44,908,544
    constexpr size_t XPAD = 0;                         // 8*66*66*256*2 = 17,842,176
    constexpr size_t WTK  = 17842176;                  // 9*128*256*2   =    589,824
    constexpr size_t WTV  = 18432000;                  // 9*256*256*2   =  1,179,648
    constexpr size_t KT   = 19611648;                  // 8*4096*128*2  =  8,388,608
    constexpr size_t VB   = 28000256;                  // 8*256*4096*2  = 16,777,216
    constexpr size_t SQ   = 44777472;                  // 8*4096*4      =    131,072

    ushort* xpad = (ushort*)(ws + XPAD);
    ushort* wtk  = (ushort*)(ws + WTK);
    ushort* wtv  = (ushort*)(ws + WTV);
    ushort* ktw  = (ushort*)(ws + KT);
    ushort* vbw  = (ushort*)(ws + VB);
    float*  sqw  = (float*)(ws + SQ);

    pad_transpose<<<dim3(2048), 256, 0, stream>>>(x, xpad);
    repack_w<<<dim3(384), 256, 0, stream>>>(kw, vw, wtk, wtv);
    conv_k<<<dim3(512), 256, 0, stream>>>(xpad, wtk, kbias, ktw, sqw);
    conv_v<<<dim3(512), 256, 0, stream>>>(xpad, wtv, vbias, out, vbw);
    attn_kernel<<<dim3(1024), 256, 0, stream>>>(ktw, vbw, sqw, out);
}

// Round 22
// 243.208 us; speedup vs baseline: 6.2177x; 1.2374x over previous
//
#include <hip/hip_runtime.h>
#include <hip/hip_bf16.h>
#include <cstdint>

// Problem constants
constexpr int Bb = 8, Cc = 256, Hh = 64, Ww = 64, Nn = 4096;
constexpr int KD = 128, VD = 256, HP = 66; // HP = padded spatial (64+2)

typedef __attribute__((ext_vector_type(8))) short short8_t;   // 8 bf16 MFMA frag
typedef __attribute__((ext_vector_type(4))) short shortx4;    // 4 bf16 packed store
typedef __attribute__((ext_vector_type(4))) float floatx4;    // MFMA accumulator

// kScale = log2(e)/sqrt(128). Softmax column factor exp2(-kScale*sq_j) cancels
// in normalization -> P' = exp2(2*kScale*dot - kScale*sq_i), out = V P'/colsum.
constexpr float kScale = 0.08838834764831845f * 1.4426950408889634f;
constexpr float kTwoK  = 2.0f * kScale;

static __device__ __forceinline__ ushort f2bf(float f) {
    union { float f; uint32_t u; } v{f};
    uint32_t r = v.u + 0x7FFFu + ((v.u >> 16) & 1u);  // RNE
    return (ushort)(r >> 16);
}
static __device__ __forceinline__ float bf2f(ushort b) {
    union { uint32_t u; float f; } v{(uint32_t)b << 16};
    return v.f;
}
// pack two f32 -> two bf16 in one u32 (RNE), single HW inst
static __device__ __forceinline__ uint32_t pk_bf16(float a, float b) {
    uint32_t r;
    asm("v_cvt_pk_bf16_f32 %0, %1, %2" : "=v"(r) : "v"(a), "v"(b));
    return r;
}
// raw v_exp_f32 (2^x) — args in [-126, 6]
static __device__ __forceinline__ float exp2_raw(float x) {
    float r;
    asm("v_exp_f32 %0, %1" : "=v"(r) : "v"(x));
    return r;
}

// async global->LDS, 16B per lane; lds base must be wave-uniform (HW adds lane*16)
static __device__ __forceinline__ void gload_lds16(const void* g, void* l) {
    __builtin_amdgcn_global_load_lds((const __attribute__((address_space(1))) uint32_t*)g,
                                     (__attribute__((address_space(3))) uint32_t*)l, 16, 0, 0);
}

// ---------------------------------------------------------------------------
// K1: x[b][c][y][x] (f32) -> xpad[b][y+1][x+1][c] (bf16, channel-last).
// Border zeroing folded in (no separate memset launch).  [r16-verified]
__global__ __launch_bounds__(256) void pad_transpose(const float* __restrict__ x,
                                                     ushort* __restrict__ xpad) {
    int bid = blockIdx.x;
    int b = bid & 7, rest = bid >> 3;
    int y = rest & 63, cg = rest >> 6;   // cg: 64-channel group
    int t = threadIdx.x;
    __shared__ float tile[64][65];
    int xcol = t & 63;
    int crow = t >> 6;  // 0..3
    const float* xb = x + ((size_t)(b * Cc + cg * 64) * Nn) + y * 64;
#pragma unroll
    for (int i = 0; i < 16; i++) {
        int c = crow + i * 4;
        tile[c][xcol] = xb[(size_t)c * Nn + xcol];
    }

    // border zeroing for this (b, cg) slice
    ushort* xbb = xpad + ((size_t)b * HP * HP) * Cc + cg * 64;
    if (y == 0) {
        for (int idx = t; idx < HP * 64; idx += 256) {
            int xx = idx >> 6, c = idx & 63;
            xbb[(size_t)xx * Cc + c] = 0;                         // row 0
        }
    }
    if (y == 63) {
        for (int idx = t; idx < HP * 64; idx += 256) {
            int xx = idx >> 6, c = idx & 63;
            xbb[((size_t)65 * HP + xx) * Cc + c] = 0;             // row 65
        }
    }
    {
        int c = t & 63, which = t >> 6;
        if (which < 2) {
            int xx = which * 65;                                  // cols 0, 65
            xbb[((size_t)(y + 1) * HP + xx) * Cc + c] = 0;
        }
    }

    __syncthreads();
    int c = t & 63;
    int x4 = t >> 6;
    ushort* dst = xpad + (((size_t)(b * HP + (y + 1)) * HP) + 1) * Cc + cg * 64 + c;
#pragma unroll
    for (int i = 0; i < 16; i++) {
        int xx = x4 + i * 4;
        dst[(size_t)xx * Cc] = f2bf(tile[c][xx]);
    }
}

// ---------------------------------------------------------------------------
// K2: repack weights w[oc][c][3][3] (f32) -> wt[r][oc][c] (bf16), r = dy*3+dx
__global__ __launch_bounds__(256) void repack_w(const float* __restrict__ kw,
                                                const float* __restrict__ vw,
                                                ushort* __restrict__ wtk,
                                                ushort* __restrict__ wtv) {
    int idx = blockIdx.x * 256 + threadIdx.x;
    const int nk = KD * Cc;   // 32768
    const int nv = VD * Cc;   // 65536
    if (idx < nk) {
        const float* src = kw + (size_t)idx * 9;
        int oc = idx / Cc, c = idx % Cc;
#pragma unroll
        for (int r = 0; r < 9; r++) wtk[((size_t)r * KD + oc) * Cc + c] = f2bf(src[r]);
    } else if (idx < nk + nv) {
        int j = idx - nk;
        const float* src = vw + (size_t)j * 9;
        int oc = j / Cc, c = j % Cc;
#pragma unroll
        for (int r = 0; r < 9; r++) wtv[((size_t)r * VD + oc) * Cc + c] = f2bf(src[r]);
    }
}

// ---------------------------------------------------------------------------
// K3a: key conv (OC=128), ONE row/block (512 blocks -> 2/CU), weight slab
// LDS-staged. Epilogue fuses sq2 = kScale * sum(bf16(kt)^2).  [r14-proven]
__global__ __launch_bounds__(256) void conv_k(const ushort* __restrict__ xpad,
                                              const ushort* __restrict__ wt,
                                              const float* __restrict__ bias,
                                              ushort* __restrict__ kt_out,
                                              float* __restrict__ sq_out) {
    int bid = blockIdx.x;
    int b = bid & 7, y = bid >> 3;
    int lane = threadIdx.x & 63, wv = threadIdx.x >> 6;
    int l15 = lane & 15, g = lane >> 4;
    const int swzA = l15 & 7;

    __shared__ ushort wslab[2][128 * 128];   // 2 x 32KB weight half-slabs

    size_t wsoff[8];
    int ldsrow[8];
#pragma unroll
    for (int h = 0; h < 8; h++) {
        int row = wv * 32 + h * 4 + (lane >> 4);      // oc row this lane stages
        wsoff[h] = (size_t)row * Cc + (((lane & 15) ^ (row & 7)) * 8);
        ldsrow[h] = (wv * 32 + h * 4) * 128;
    }

    floatx4 acc[8];
#pragma unroll
    for (int m = 0; m < 8; m++) acc[m] = (floatx4){0.f, 0.f, 0.f, 0.f};

    const ushort* xb = xpad + ((size_t)b * HP * HP) * Cc;
    int xcol = wv * 16 + l15;  // output x position (wave's 16 columns)

    auto stage = [&](int hs, int bi) {
        int r = hs >> 1, hc = hs & 1;
        const ushort* wb = wt + ((size_t)r * KD) * Cc + hc * 128;
#pragma unroll
        for (int h = 0; h < 8; h++)
            gload_lds16(wb + wsoff[h], &wslab[bi][ldsrow[h]]);
    };

    stage(0, 0);
    __syncthreads();   // implicit vmcnt(0): slab 0 resident

#pragma unroll 1
    for (int hs = 0; hs < 18; ++hs) {
        int bi = hs & 1;
        if (hs < 17) stage(hs + 1, bi ^ 1);   // prefetch; drained by end barrier

        int r = hs >> 1, hc = hs & 1;
        int dy = r / 3, dx = r % 3;
        const ushort* bsrc = xb + ((size_t)(y + dy) * HP + xcol + dx) * Cc + hc * 128 + g * 8;
#pragma unroll
        for (int cc = 0; cc < 4; cc++) {      // 4 k-steps of 32 channels
            short8_t bfrag = *(const short8_t*)(bsrc + cc * 32);
#pragma unroll
            for (int m = 0; m < 8; m++) {
                short8_t afrag = *(const short8_t*)&wslab[bi][(m * 16 + l15) * 128 + ((cc * 4 + g) ^ swzA) * 8];
                acc[m] = __builtin_amdgcn_mfma_f32_16x16x32_bf16(afrag, bfrag, acc[m], 0, 0, 0);
            }
        }
        __syncthreads();   // reads done + prefetch drained
    }

    int pos = y * 64 + xcol;
    ushort* kt = kt_out + ((size_t)(b * Nn + pos)) * KD;
    float ssum = 0.f;
#pragma unroll
    for (int m = 0; m < 8; m++) {
        floatx4 bv = *(const floatx4*)(bias + m * 16 + g * 4);
        shortx4 pk;
#pragma unroll
        for (int r = 0; r < 4; r++) {
            pk[r] = (short)f2bf(acc[m][r] + bv[r]);
            float q = bf2f((ushort)pk[r]);   // bf16-rounded (diag-exact sq)
            ssum += q * q;
        }
        *(shortx4*)(kt + m * 16 + g * 4) = pk;
    }
    ssum += __shfl_xor(ssum, 16, 64);
    ssum += __shfl_xor(ssum, 32, 64);
    if (g == 0) sq_out[b * Nn + pos] = ssum * kScale;
}

// ---------------------------------------------------------------------------
// K3b: value conv (OC=256), TWO rows/block (512 blocks -> 2/CU).  [r14-proven]
__global__ __launch_bounds__(256) void conv_v(const ushort* __restrict__ xpad,
                                              const ushort* __restrict__ wt,
                                              const float* __restrict__ bias,
                                              float* __restrict__ f32_out,
                                              ushort* __restrict__ vb_out) {
    int bid = blockIdx.x;
    int b = bid & 7;
    int ocg = (bid >> 3) & 1;
    int y0 = (bid >> 4) * 2;
    int lane = threadIdx.x & 63, wv = threadIdx.x >> 6;
    int l15 = lane & 15, g = lane >> 4;
    int oc0 = ocg * 128;
    const int swzA = l15 & 7;

    __shared__ ushort wslab[2][128 * 128];   // 2 x 32KB weight half-slabs

    size_t wsoff[8];
    int ldsrow[8];
#pragma unroll
    for (int h = 0; h < 8; h++) {
        int row = wv * 32 + h * 4 + (lane >> 4);      // oc row this lane stages
        wsoff[h] = (size_t)row * Cc + (((lane & 15) ^ (row & 7)) * 8);
        ldsrow[h] = (wv * 32 + h * 4) * 128;
    }

    floatx4 acc[8][2];
#pragma unroll
    for (int m = 0; m < 8; m++)
#pragma unroll
        for (int rr = 0; rr < 2; rr++) acc[m][rr] = (floatx4){0.f, 0.f, 0.f, 0.f};

    const ushort* xb = xpad + ((size_t)b * HP * HP) * Cc;
    int xcol = wv * 16 + l15;  // output x position (wave's 16 columns)

    auto stage = [&](int hs, int bi) {
        int r = hs >> 1, hc = hs & 1;
        const ushort* wb = wt + ((size_t)r * VD + oc0) * Cc + hc * 128;
#pragma unroll
        for (int h = 0; h < 8; h++)
            gload_lds16(wb + wsoff[h], &wslab[bi][ldsrow[h]]);
    };

    stage(0, 0);
    __syncthreads();   // implicit vmcnt(0): slab 0 resident

#pragma unroll 1
    for (int hs = 0; hs < 18; ++hs) {
        int bi = hs & 1;
        if (hs < 17) stage(hs + 1, bi ^ 1);   // prefetch; drained by end barrier

        int r = hs >> 1, hc = hs & 1;
        int dy = r / 3, dx = r % 3;
        const ushort* bsrc0 = xb + ((size_t)(y0 + dy) * HP + xcol + dx) * Cc + hc * 128 + g * 8;
        const ushort* bsrc1 = bsrc0 + (size_t)HP * Cc;   // row y0+1
#pragma unroll
        for (int cc = 0; cc < 4; cc++) {      // 4 k-steps of 32 channels
            short8_t bfragA = *(const short8_t*)(bsrc0 + cc * 32);
            short8_t bfragB = *(const short8_t*)(bsrc1 + cc * 32);
#pragma unroll
            for (int m = 0; m < 8; m++) {
                short8_t afrag = *(const short8_t*)&wslab[bi][(m * 16 + l15) * 128 + ((cc * 4 + g) ^ swzA) * 8];
                acc[m][0] = __builtin_amdgcn_mfma_f32_16x16x32_bf16(afrag, bfragA, acc[m][0], 0, 0, 0);
                acc[m][1] = __builtin_amdgcn_mfma_f32_16x16x32_bf16(afrag, bfragB, acc[m][1], 0, 0, 0);
            }
        }
        __syncthreads();   // reads done + prefetch drained
    }

#pragma unroll
    for (int rr = 0; rr < 2; rr++) {
        int pos = (y0 + rr) * 64 + xcol;
#pragma unroll
        for (int m = 0; m < 8; m++) {
            floatx4 bv = *(const floatx4*)(bias + oc0 + m * 16 + g * 4);
#pragma unroll
            for (int r = 0; r < 4; r++) {
                int oc = oc0 + m * 16 + g * 4 + r;
                float v = acc[m][rr][r] + bv[r];
                f32_out[((size_t)(b * 512 + oc)) * Nn + pos] = v;       // d_out f32
                vb_out[((size_t)(b * VD + oc)) * Nn + pos] = f2bf(v);   // bf16 for PV
            }
        }
    }
}

// ---------------------------------------------------------------------------
// K5: fused attention — EXACT round-15 kernel (best measured: 143.0us).
// pt eliminated via permuted K-row staging: phys slot p = f*16+4g+r of bufK
// holds logical i = 32*(f&1) + 8g + 4*(f>>1) + r, so the S D-layout packed
// through cvt_pk IS the PV B-frag in-lane (no LDS round-trip, no shuffles).
// Waves fully independent (own 16 j, all 256 vd); 2 barriers/iter.
// LDS 48KB; grid 512 (2 blk/CU); VGPR 84; conflicts ~8.4e6.
__global__ __launch_bounds__(256, 3) void attn_kernel(const ushort* __restrict__ kt,
                                                      const ushort* __restrict__ vb,
                                                      const float* __restrict__ sq2,
                                                      float* __restrict__ out) {
    int bid = blockIdx.x;
    int b = bid & 7, jt = bid >> 3;
    int lane = threadIdx.x & 63, wv = threadIdx.x >> 6;
    int l15 = lane & 15, g = lane >> 4;

    __shared__ ushort bufK[64 * 128];      // 16KB: [phys row][swizzled 16B units]
    __shared__ ushort bufV[256 * 64];      // 32KB: [vd][swizzled 16B units]

    const ushort* ktb = kt + ((size_t)b * Nn) * KD;
    const ushort* vbb = vb + ((size_t)b * VD) * Nn;
    const float* sqb = sq2 + b * Nn;

    // K staging with phys->logical row permutation
    const ushort* skp[4];
#pragma unroll
    for (int h = 0; h < 4; h++) {
        int sub = lane >> 4;
        int pr = h * 4 + sub;                                    // p & 15
        int ilog = ((wv & 1) << 5) + (h << 3) + ((wv >> 1) << 2) + sub;
        skp[h] = ktb + (size_t)ilog * KD + ((l15 ^ (pr & 7)) * 8);
    }
    const ushort* svp[8];
#pragma unroll
    for (int h = 0; h < 8; h++) {
        int vd = wv * 64 + h * 8 + (lane >> 3);
        svp[h] = vbb + (size_t)vd * Nn + (((lane & 7) ^ (vd & 7)) * 8);
    }

    // kj B-frags for this wave's 16 j columns
    int j = jt * 64 + wv * 16 + l15;
    short8_t kj[4];
#pragma unroll
    for (int kk = 0; kk < 4; kk++)
        kj[kk] = *(const short8_t*)(ktb + (size_t)j * KD + kk * 32 + g * 8);

    floatx4 acc[16];   // all 256 vd for own 16 j
#pragma unroll
    for (int m = 0; m < 16; m++) acc[m] = (floatx4){0.f, 0.f, 0.f, 0.f};
    float dsum = 0.f;
    const int swzA = l15 & 7;

    // prologue: stage K(0), V(0)
#pragma unroll
    for (int h = 0; h < 4; h++) gload_lds16(skp[h], &bufK[(wv * 16 + h * 4) * 128]);
#pragma unroll
    for (int h = 0; h < 8; h++) gload_lds16(svp[h], &bufV[(wv * 64 + h * 8) * 64]);
    __syncthreads();   // implicit vmcnt(0): both tiles resident

#pragma unroll 1
    for (int it = 0; it < 64; ++it) {
        int i0 = it * 64;

        // S-phase: 16 afr reads, 16 MFMAs (phys-row indexed)
        floatx4 sacc[4];
#pragma unroll
        for (int f = 0; f < 4; f++) sacc[f] = (floatx4){0.f, 0.f, 0.f, 0.f};
#pragma unroll
        for (int kk = 0; kk < 4; kk++) {
#pragma unroll
            for (int f = 0; f < 4; f++) {
                short8_t afr = *(const short8_t*)&bufK[(f * 16 + l15) * 128 + ((kk * 4 + g) ^ swzA) * 8];
                sacc[f] = __builtin_amdgcn_mfma_f32_16x16x32_bf16(afr, kj[kk], sacc[f], 0, 0, 0);
            }
        }
        __syncthreads();   // sync1: all waves done reading bufK; bufV resident

        // K(it+1) prefetch (WAR-safe; drains at sync2; window = transform+PV)
        if (it < 63) {
#pragma unroll
            for (int h = 0; h < 4; h++)
                gload_lds16(skp[h] + (size_t)(i0 + 64) * KD, &bufK[(wv * 16 + h * 4) * 128]);
        }

        // transform (registers only): sacc[f][r] holds logical
        // i = 32*(f&1) + 8g + 4*(f>>1) + r; P' = exp2(2k*dot - k*sq_i)
        uint32_t w2[4][2];
#pragma unroll
        for (int f = 0; f < 4; f++) {
            floatx4 sqi = *(const floatx4*)(sqb + i0 + ((f & 1) << 5) + (g << 3) + ((f >> 1) << 2));
            float p0 = exp2_raw(sacc[f][0] * kTwoK - sqi[0]);
            float p1 = exp2_raw(sacc[f][1] * kTwoK - sqi[1]);
            float p2 = exp2_raw(sacc[f][2] * kTwoK - sqi[2]);
            float p3 = exp2_raw(sacc[f][3] * kTwoK - sqi[3]);
            dsum += (p0 + p1) + (p2 + p3);
            w2[f][0] = pk_bf16(p0, p1);
            w2[f][1] = pk_bf16(p2, p3);
        }

        // PV: B-frag is lane-local; 32 vfr reads, 32 MFMAs
#pragma unroll
        for (int k2 = 0; k2 < 2; k2++) {
            union { uint32_t u[4]; short8_t s; } pu;
            pu.u[0] = w2[k2][0];
            pu.u[1] = w2[k2][1];
            pu.u[2] = w2[k2 | 2][0];
            pu.u[3] = w2[k2 | 2][1];
            short8_t pfr = pu.s;
#pragma unroll
            for (int m = 0; m < 16; m++) {
                short8_t vfr = *(const short8_t*)&bufV[(m * 16 + l15) * 64 + ((k2 * 4 + g) ^ swzA) * 8];
                acc[m] = __builtin_amdgcn_mfma_f32_16x16x32_bf16(vfr, pfr, acc[m], 0, 0, 0);
            }
        }
        __syncthreads();   // sync2: bufV reads done; K prefetch drained

        // V(it+1) prefetch (drains at next iter's sync1)
        if (it < 63) {
#pragma unroll
            for (int h = 0; h < 8; h++)
                gload_lds16(svp[h] + (i0 + 64), &bufV[(wv * 64 + h * 8) * 64]);
        }
    }

    // denominator: the 4 g-lanes of column j hold disjoint i-slices
    dsum += __shfl_xor(dsum, 16, 64);
    dsum += __shfl_xor(dsum, 32, 64);
    float rden = 1.f / dsum;

    // output: vd = m*16 + g*4 + r, column j
    float* ob = out + ((size_t)(b * 512 + 256)) * Nn + j;
#pragma unroll
    for (int m = 0; m < 16; m++) {
#pragma unroll
        for (int r = 0; r < 4; r++) {
            int vd = m * 16 + g * 4 + r;
            ob[(size_t)vd * Nn] = acc[m][r] * rden;
        }
    }
}

// ---------------------------------------------------------------------------
extern "C" void kernel_launch(void* const* d_in, const int* in_sizes, int n_in,
                              void* d_out, int out_size, void* d_ws, size_t ws_size,
                              hipStream_t stream) {
    const float* x     = (const float*)d_in[0];
    const float* kw    = (const float*)d_in[1];
    const float* kbias = (const float*)d_in[2];
    const float* vw    = (const float*)d_in[3];
    const float* vbias = (const float*)d_in[4];
    float* out = (float*)d_out;  // reference output dtype is FLOAT32
    char* ws = (char*)d_ws;

    // workspace layout (bytes) — total 44,908,544
    constexpr size_t XPAD = 0;                         // 8*66*66*256*2 = 17,842,176
    constexpr size_t WTK  = 17842176;                  // 9*128*256*2   =    589,824
    constexpr size_t WTV  = 18432000;                  // 9*256*256*2   =  1,179,648
    constexpr size_t KT   = 19611648;                  // 8*4096*128*2  =  8,388,608
    constexpr size_t VB   = 28000256;                  // 8*256*4096*2  = 16,777,216
    constexpr size_t SQ   = 44777472;                  // 8*4096*4      =    131,072

    ushort* xpad = (ushort*)(ws + XPAD);
    ushort* wtk  = (ushort*)(ws + WTK);
    ushort* wtv  = (ushort*)(ws + WTV);
    ushort* ktw  = (ushort*)(ws + KT);
    ushort* vbw  = (ushort*)(ws + VB);
    float*  sqw  = (float*)(ws + SQ);

    pad_transpose<<<dim3(2048), 256, 0, stream>>>(x, xpad);
    repack_w<<<dim3(384), 256, 0, stream>>>(kw, vw, wtk, wtv);
    conv_k<<<dim3(512), 256, 0, stream>>>(xpad, wtk, kbias, ktw, sqw);
    conv_v<<<dim3(512), 256, 0, stream>>>(xpad, wtv, vbias, out, vbw);
    attn_kernel<<<dim3(512), 256, 0, stream>>>(ktw, vbw, sqw, out);
}